// Round 1
// baseline (815.813 us; speedup 1.0000x reference)
//
#include <hip/hip_runtime.h>
#include <hip/hip_bf16.h>

#define NLB 4096
#define NULB 6144
#define NROWS 16384   // 4096 + 2*6144
#define DD 128
#define NC 10

typedef __bf16 bf16_t;
typedef bf16_t bf16x8 __attribute__((ext_vector_type(8)));
typedef float f32x4 __attribute__((ext_vector_type(4)));
typedef float f32x2 __attribute__((ext_vector_type(2)));
typedef unsigned int u32;

// ---------------- L2-normalize rows of [lb_feat; anchor; positive] -> bf16 F ----------------
__global__ void knorm(const float* __restrict__ lb, const float* __restrict__ an,
                      const float* __restrict__ po, bf16_t* __restrict__ F) {
  int row = blockIdx.x;
  int lane = threadIdx.x;  // 64
  const float* src;
  if (row < NLB) src = lb + (size_t)row * DD;
  else if (row < NLB + NULB) src = an + (size_t)(row - NLB) * DD;
  else src = po + (size_t)(row - NLB - NULB) * DD;
  float2 v = ((const float2*)src)[lane];
  float ss = v.x * v.x + v.y * v.y;
#pragma unroll
  for (int off = 32; off >= 1; off >>= 1) ss += __shfl_xor(ss, off);
  float n = fmaxf(sqrtf(ss), 1e-12f);
  float inv = 1.0f / n;
  union { bf16_t h[2]; u32 u; } pk;
  pk.h[0] = (bf16_t)(v.x * inv);
  pk.h[1] = (bf16_t)(v.y * inv);
  ((u32*)F)[(size_t)row * (DD / 2) + lane] = pk.u;
}

// ---------------- labeled rows: copy one-hot into V, count classes ----------------
__global__ void klb(const float* __restrict__ onehot, float* __restrict__ V,
                    float* __restrict__ cls) {
  __shared__ float lcnt[NC];
  int t = threadIdx.x;  // 256
  if (t < NC) lcnt[t] = 0.0f;
  __syncthreads();
  int row = blockIdx.x * 256 + t;  // < 4096 always
  int idx = 0;
#pragma unroll
  for (int c = 0; c < NC; ++c) {
    float v = onehot[(size_t)row * NC + c];
    V[(size_t)row * NC + c] = v;
    if (v == 1.0f) idx = c;
  }
  atomicAdd(&lcnt[idx], 1.0f);
  __syncthreads();
  if (t < NC) atomicAdd(&cls[t], lcnt[t]);
}

// ---------------- unlabeled rows: pick view, mask, softmax/T into V (twice), count ----------------
__global__ void kulb(const float* __restrict__ l1, const float* __restrict__ l2,
                     float* __restrict__ V, float* __restrict__ cls) {
  int r = blockIdx.x * 256 + threadIdx.x;  // < 6144 always
  float a[NC], b[NC];
#pragma unroll
  for (int c = 0; c < NC; ++c) { a[c] = l1[(size_t)r * NC + c]; b[c] = l2[(size_t)r * NC + c]; }
  float m1 = a[0], m2 = b[0];
#pragma unroll
  for (int c = 1; c < NC; ++c) { m1 = fmaxf(m1, a[c]); m2 = fmaxf(m2, b[c]); }
  float s1 = 0.0f, s2 = 0.0f;
#pragma unroll
  for (int c = 0; c < NC; ++c) {
    s1 += expf(2.0f * (a[c] - m1));
    s2 += expf(2.0f * (b[c] - m2));
  }
  // max(prob1) = 1/s1 ; take1 = max(prob1) >= max(prob2)  <=>  s1 <= s2
  bool take1 = (s1 <= s2);
  float g[NC];
#pragma unroll
  for (int c = 0; c < NC; ++c) g[c] = take1 ? a[c] : b[c];
  // mask: softmax(g) >= 0.95 (at most one class can pass)
  float mg = g[0];
#pragma unroll
  for (int c = 1; c < NC; ++c) mg = fmaxf(mg, g[c]);
  float e[NC]; float sg = 0.0f;
#pragma unroll
  for (int c = 0; c < NC; ++c) { e[c] = expf(g[c] - mg); sg += e[c]; }
  float msk[NC];
#pragma unroll
  for (int c = 0; c < NC; ++c) msk[c] = ((e[c] / sg) >= 0.95f) ? g[c] : 0.0f;
  // argmax / valid for class counts (counted twice: concat duplication)
  float mx = msk[0]; int mi = 0;
#pragma unroll
  for (int c = 1; c < NC; ++c) if (msk[c] > mx) { mx = msk[c]; mi = c; }
  if (mx != 0.0f) atomicAdd(&cls[mi], 2.0f);
  // prob = softmax(msk / 0.5)
  float mm = 2.0f * msk[0];
#pragma unroll
  for (int c = 1; c < NC; ++c) mm = fmaxf(mm, 2.0f * msk[c]);
  float p[NC]; float sp = 0.0f;
#pragma unroll
  for (int c = 0; c < NC; ++c) { p[c] = expf(2.0f * msk[c] - mm); sp += p[c]; }
#pragma unroll
  for (int c = 0; c < NC; ++c) {
    float pv = p[c] / sp;
    V[(size_t)(NLB + r) * NC + c] = pv;
    V[(size_t)(NLB + NULB + r) * NC + c] = pv;
  }
}

// ---------------- denominators ----------------
__global__ void kdenom(const float* __restrict__ cls, float* __restrict__ invden) {
  int c = threadIdx.x;
  float tot = 0.0f;
#pragma unroll
  for (int i = 0; i < NC; ++i) tot += cls[i];
  if (c < NC) {
    float d = cls[c];
    d = (d == 0.0f) ? tot : d;
    invden[c] = 1.0f / d;
  }
}

// ---------------- fused attention: softmax(F F^T / 0.5) @ V, / denom ----------------
// Block: 256 threads (4 waves). Each wave owns a 16-row i-tile (i0..i0+15).
// j loop: stages of 64 rows of F (bf16, padded LDS) + V (padded to 12 floats).
// MFMA computes C^T tiles: lane (q, r): j_local = q*4+reg, i_local = r.
// logits in [-2,2] (unit-norm feats) -> no online max needed; plain sums.
#define BI 64
#define BJ 64
#define LROW 136  // 128 + 8 bf16 pad: keeps 16B alignment, uniform bank groups

__launch_bounds__(256)
__global__ void kattn(const bf16_t* __restrict__ F, const float* __restrict__ V,
                      const float* __restrict__ invden, float* __restrict__ out) {
  __shared__ bf16_t Fs[BJ * LROW];  // 17408 B
  __shared__ float Vs[BJ * 12];     // 3072 B
  int t = threadIdx.x;
  int lane = t & 63;
  int wave = t >> 6;
  int q = lane >> 4;
  int r = lane & 15;
  int i0 = blockIdx.x * BI + wave * 16;

  // B-operand fragments: rows of F for this wave's i-tile (constant over j loop)
  // B[k=q*8+j][n=r] = F[i0+r][k]
  bf16x8 bfr[4];
#pragma unroll
  for (int kk = 0; kk < 4; ++kk)
    bfr[kk] = *(const bf16x8*)(F + (size_t)(i0 + r) * DD + kk * 32 + q * 8);

  f32x4 accA = {0.f, 0.f, 0.f, 0.f};
  f32x4 accB = {0.f, 0.f, 0.f, 0.f};
  f32x2 accC = {0.f, 0.f};
  float accsum = 0.0f;

  for (int j0 = 0; j0 < NROWS; j0 += BJ) {
    __syncthreads();
    // stage F rows j0..j0+63 into padded LDS (uint4 per thread x4)
#pragma unroll
    for (int it = 0; it < 4; ++it) {
      int chunk = t + it * 256;   // 0..1023
      int row = chunk >> 4;
      int col = chunk & 15;
      uint4 dat = *(const uint4*)(F + (size_t)(j0 + row) * DD + col * 8);
      *(uint4*)&Fs[row * LROW + col * 8] = dat;
    }
    // stage V rows (640 dwords) into padded [64][12] layout
#pragma unroll
    for (int it = 0; it < 3; ++it) {
      int d = t + it * 256;
      if (d < BJ * NC) {
        int vrow = d / NC;
        int vc = d - vrow * NC;
        Vs[vrow * 12 + vc] = V[(size_t)j0 * NC + d];
      }
    }
    __syncthreads();
#pragma unroll
    for (int js = 0; js < 4; ++js) {
      f32x4 cfr = {0.f, 0.f, 0.f, 0.f};
      const bf16_t* fs = &Fs[(js * 16 + r) * LROW + q * 8];
#pragma unroll
      for (int kk = 0; kk < 4; ++kk) {
        bf16x8 afr = *(const bf16x8*)(fs + kk * 32);  // A[m=r][k=q*8+j] = F[j0+js*16+r][k]
        cfr = __builtin_amdgcn_mfma_f32_16x16x32_bf16(afr, bfr[kk], cfr, 0, 0, 0);
      }
      // cfr[rg] = dot(F[j0+js*16+q*4+rg], F[i0+r])  (C layout: row=q*4+reg, col=r)
#pragma unroll
      for (int rg = 0; rg < 4; ++rg) {
        float w = exp2f(cfr[rg] * 2.8853900817779268f);  // exp(2*dot) = 2^(dot*2*log2 e)
        accsum += w;
        const float* vr = &Vs[(js * 16 + q * 4 + rg) * 12];
        f32x4 v0 = *(const f32x4*)vr;
        f32x4 v1 = *(const f32x4*)(vr + 4);
        f32x2 v2 = *(const f32x2*)(vr + 8);
        accA += v0 * w;
        accB += v1 * w;
        accC += v2 * w;
      }
    }
  }

  // reduce across the 4 quads (lanes sharing r hold disjoint j-quarters)
#pragma unroll
  for (int off = 16; off <= 32; off <<= 1) {
    accsum += __shfl_xor(accsum, off);
#pragma unroll
    for (int k = 0; k < 4; ++k) {
      accA[k] += __shfl_xor(accA[k], off);
      accB[k] += __shfl_xor(accB[k], off);
    }
    accC[0] += __shfl_xor(accC[0], off);
    accC[1] += __shfl_xor(accC[1], off);
  }

  if (q == 0) {
    float rs = 1.0f / accsum;
    int orow = i0 + r;
    float* op = out + (size_t)orow * NC;
    op[0] = accA[0] * rs * invden[0];
    op[1] = accA[1] * rs * invden[1];
    op[2] = accA[2] * rs * invden[2];
    op[3] = accA[3] * rs * invden[3];
    op[4] = accB[0] * rs * invden[4];
    op[5] = accB[1] * rs * invden[5];
    op[6] = accB[2] * rs * invden[6];
    op[7] = accB[3] * rs * invden[7];
    op[8] = accC[0] * rs * invden[8];
    op[9] = accC[1] * rs * invden[9];
  }
}

extern "C" void kernel_launch(void* const* d_in, const int* in_sizes, int n_in,
                              void* d_out, int out_size, void* d_ws, size_t ws_size,
                              hipStream_t stream) {
  const float* anchor   = (const float*)d_in[0];  // 6144x128
  const float* positive = (const float*)d_in[1];  // 6144x128
  const float* lbfeat   = (const float*)d_in[2];  // 4096x128
  const float* onehot   = (const float*)d_in[3];  // 4096x10
  const float* l1       = (const float*)d_in[4];  // 6144x10
  const float* l2       = (const float*)d_in[5];  // 6144x10
  float* out = (float*)d_out;                     // 16384x10

  char* ws = (char*)d_ws;
  bf16_t* F     = (bf16_t*)ws;                         // 16384*128*2 = 4 MiB
  float*  V     = (float*)(ws + 4194304);              // 16384*10*4  = 640 KiB
  float*  cls   = (float*)(ws + 4194304 + 655360);     // 10 floats
  float*  invden= (float*)(ws + 4194304 + 655360 + 256);

  hipMemsetAsync(cls, 0, NC * sizeof(float), stream);
  knorm<<<NROWS, 64, 0, stream>>>(lbfeat, anchor, positive, F);
  klb<<<NLB / 256, 256, 0, stream>>>(onehot, V, cls);
  kulb<<<NULB / 256, 256, 0, stream>>>(l1, l2, V, cls);
  kdenom<<<1, 64, 0, stream>>>(cls, invden);
  kattn<<<NROWS / BI, 256, 0, stream>>>(F, V, invden, out);
}

// Round 2
// 271.558 us; speedup vs baseline: 3.0042x; 3.0042x over previous
//
#include <hip/hip_runtime.h>
#include <hip/hip_bf16.h>

#define NLB 4096
#define NULB 6144
#define NROWS 16384   // 4096 + 2*6144
#define DD 128
#define NC 10
#define SEG 8
#define JSEG (NROWS / SEG)   // 2048
#define BI 128               // i-rows per block (8 waves x 16)
#define BJ 64                // j-rows per LDS tile

typedef __bf16 bf16_t;
typedef bf16_t bf16x8 __attribute__((ext_vector_type(8)));
typedef float f32x4 __attribute__((ext_vector_type(4)));
typedef float f32x2 __attribute__((ext_vector_type(2)));
typedef unsigned int u32;

// ---------------- L2-normalize rows of [lb_feat; anchor; positive] -> bf16 F ----------------
__global__ void knorm(const float* __restrict__ lb, const float* __restrict__ an,
                      const float* __restrict__ po, bf16_t* __restrict__ F) {
  int row = blockIdx.x;
  int lane = threadIdx.x;  // 64
  const float* src;
  if (row < NLB) src = lb + (size_t)row * DD;
  else if (row < NLB + NULB) src = an + (size_t)(row - NLB) * DD;
  else src = po + (size_t)(row - NLB - NULB) * DD;
  float2 v = ((const float2*)src)[lane];
  float ss = v.x * v.x + v.y * v.y;
#pragma unroll
  for (int off = 32; off >= 1; off >>= 1) ss += __shfl_xor(ss, off);
  float inv = 1.0f / fmaxf(sqrtf(ss), 1e-12f);
  union { bf16_t h[2]; u32 u; } pk;
  pk.h[0] = (bf16_t)(v.x * inv);
  pk.h[1] = (bf16_t)(v.y * inv);
  ((u32*)F)[(size_t)row * (DD / 2) + lane] = pk.u;
}

// ---------------- build V rows + class counts (fused lb/ulb) ----------------
// blocks 0..15: labeled rows (one-hot copy). blocks 16..39: unlabeled rows.
__global__ void kprep(const float* __restrict__ onehot, const float* __restrict__ l1,
                      const float* __restrict__ l2, float* __restrict__ V,
                      float* __restrict__ cls) {
  __shared__ float lcnt[NC];
  int t = threadIdx.x;
  if (t < NC) lcnt[t] = 0.0f;
  __syncthreads();
  int gid = blockIdx.x * 256 + t;
  if (gid < NLB) {
    int idx = 0;
#pragma unroll
    for (int c = 0; c < NC; ++c) {
      float v = onehot[(size_t)gid * NC + c];
      V[(size_t)gid * NC + c] = v;
      if (v == 1.0f) idx = c;
    }
    atomicAdd(&lcnt[idx], 1.0f);
  } else {
    int r = gid - NLB;
    float a[NC], b[NC];
#pragma unroll
    for (int c = 0; c < NC; ++c) { a[c] = l1[(size_t)r * NC + c]; b[c] = l2[(size_t)r * NC + c]; }
    float m1 = a[0], m2 = b[0];
#pragma unroll
    for (int c = 1; c < NC; ++c) { m1 = fmaxf(m1, a[c]); m2 = fmaxf(m2, b[c]); }
    float s1 = 0.0f, s2 = 0.0f;
#pragma unroll
    for (int c = 0; c < NC; ++c) {
      s1 += expf(2.0f * (a[c] - m1));
      s2 += expf(2.0f * (b[c] - m2));
    }
    bool take1 = (s1 <= s2);  // max(prob1)=1/s1 >= 1/s2=max(prob2)
    float g[NC];
#pragma unroll
    for (int c = 0; c < NC; ++c) g[c] = take1 ? a[c] : b[c];
    float mg = g[0];
#pragma unroll
    for (int c = 1; c < NC; ++c) mg = fmaxf(mg, g[c]);
    float e[NC]; float sg = 0.0f;
#pragma unroll
    for (int c = 0; c < NC; ++c) { e[c] = expf(g[c] - mg); sg += e[c]; }
    float msk[NC];
#pragma unroll
    for (int c = 0; c < NC; ++c) msk[c] = ((e[c] / sg) >= 0.95f) ? g[c] : 0.0f;
    float mx = msk[0]; int mi = 0;
#pragma unroll
    for (int c = 1; c < NC; ++c) if (msk[c] > mx) { mx = msk[c]; mi = c; }
    if (mx != 0.0f) atomicAdd(&lcnt[mi], 2.0f);
    float mm = 2.0f * msk[0];
#pragma unroll
    for (int c = 1; c < NC; ++c) mm = fmaxf(mm, 2.0f * msk[c]);
    float p[NC]; float sp = 0.0f;
#pragma unroll
    for (int c = 0; c < NC; ++c) { p[c] = expf(2.0f * msk[c] - mm); sp += p[c]; }
#pragma unroll
    for (int c = 0; c < NC; ++c) {
      float pv = p[c] / sp;
      V[(size_t)(NLB + r) * NC + c] = pv;
      V[(size_t)(NLB + NULB + r) * NC + c] = pv;
    }
  }
  __syncthreads();
  if (t < NC) atomicAdd(&cls[t], lcnt[t]);
}

// ---------------- fused attention partials: exp(2*F F^T) @ V per j-segment ----------------
// grid (128, 8): x = i-block (128 rows, 8 waves x 16), y = j-segment (2048 rows).
// Fs uses a 16B-chunk XOR swizzle (phys = col ^ (row&15)) -> bank-uniform staging
// writes AND A-frag ds_read_b128 (no pad, 16 KB).
// Accumulation is additive (no online max: unit-norm dots in [-2,2]) ->
// partials atomicAdd'ed into out (numerators) and sumbuf (denominator).
__launch_bounds__(512, 8)
__global__ void kattn(const bf16_t* __restrict__ F, const float* __restrict__ V,
                      float* __restrict__ out, float* __restrict__ sumbuf) {
  __shared__ bf16_t Fs[BJ * 128];  // 16 KB, swizzled
  __shared__ float Vs[BJ * 12];    // 3 KB
  int t = threadIdx.x;
  int lane = t & 63;
  int wave = t >> 6;    // 0..7
  int q = lane >> 4;    // 0..3
  int r = lane & 15;    // 0..15
  int i0 = blockIdx.x * BI + wave * 16;
  int jbase = blockIdx.y * JSEG;

  // B-operand fragments: this wave's 16 i-rows (constant over the j loop)
  bf16x8 bfr[4];
#pragma unroll
  for (int kk = 0; kk < 4; ++kk)
    bfr[kk] = *(const bf16x8*)(F + (size_t)(i0 + r) * DD + kk * 32 + q * 8);

  f32x4 accA = {0.f, 0.f, 0.f, 0.f};
  f32x4 accB = {0.f, 0.f, 0.f, 0.f};
  f32x2 accC = {0.f, 0.f};
  float accsum = 0.0f;

  for (int jt = 0; jt < JSEG; jt += BJ) {
    int j0 = jbase + jt;
    __syncthreads();
    // stage F tile: 1024 16B-chunks, swizzled
#pragma unroll
    for (int it = 0; it < 2; ++it) {
      int cid = t + it * 512;          // 0..1023
      int row = cid >> 4;
      int col = cid & 15;
      uint4 dat = *(const uint4*)(F + (size_t)(j0 + row) * DD + col * 8);
      *(uint4*)&Fs[(row * 16 + (col ^ (row & 15))) * 8] = dat;
    }
    // stage V tile into [64][12]
#pragma unroll
    for (int it = 0; it < 2; ++it) {
      int d = t + it * 512;
      if (d < BJ * NC) {
        int vrow = d / NC;
        int vc = d - vrow * NC;
        Vs[vrow * 12 + vc] = V[(size_t)j0 * NC + d];
      }
    }
    __syncthreads();
#pragma unroll
    for (int js = 0; js < 4; ++js) {
      f32x4 cfr = {0.f, 0.f, 0.f, 0.f};
      const bf16_t* fsrow = &Fs[(js * 16 + r) * 128];
#pragma unroll
      for (int kk = 0; kk < 4; ++kk) {
        bf16x8 afr = *(const bf16x8*)(fsrow + ((kk * 4 + q) ^ r) * 8);
        cfr = __builtin_amdgcn_mfma_f32_16x16x32_bf16(afr, bfr[kk], cfr, 0, 0, 0);
      }
      // cfr[rg] = dot(F[j0+js*16+q*4+rg], F[i0+r])
#pragma unroll
      for (int rg = 0; rg < 4; ++rg) {
        float w = __builtin_amdgcn_exp2f(cfr[rg] * 2.8853900817779268f);  // exp(2*dot)
        accsum += w;
        const float* vr = &Vs[(js * 16 + q * 4 + rg) * 12];
        f32x4 v0 = *(const f32x4*)vr;
        f32x4 v1 = *(const f32x4*)(vr + 4);
        f32x2 v2 = *(const f32x2*)(vr + 8);
        accA += v0 * w;
        accB += v1 * w;
        accC += v2 * w;
      }
    }
  }

  // reduce across quads (lanes sharing r hold disjoint j quarters)
#pragma unroll
  for (int off = 16; off <= 32; off <<= 1) {
    accsum += __shfl_xor(accsum, off);
#pragma unroll
    for (int k = 0; k < 4; ++k) {
      accA[k] += __shfl_xor(accA[k], off);
      accB[k] += __shfl_xor(accB[k], off);
    }
    accC[0] += __shfl_xor(accC[0], off);
    accC[1] += __shfl_xor(accC[1], off);
  }

  if (q == 0) {
    int row = i0 + r;
    float* op = out + (size_t)row * NC;
    atomicAdd(&op[0], accA[0]);
    atomicAdd(&op[1], accA[1]);
    atomicAdd(&op[2], accA[2]);
    atomicAdd(&op[3], accA[3]);
    atomicAdd(&op[4], accB[0]);
    atomicAdd(&op[5], accB[1]);
    atomicAdd(&op[6], accB[2]);
    atomicAdd(&op[7], accB[3]);
    atomicAdd(&op[8], accC[0]);
    atomicAdd(&op[9], accC[1]);
    atomicAdd(&sumbuf[row], accsum);
  }
}

// ---------------- finalize: divide by softmax denom and class denom ----------------
__global__ void kfinal(float* __restrict__ out, const float* __restrict__ sumbuf,
                       const float* __restrict__ cls) {
  int row = blockIdx.x * 256 + threadIdx.x;  // 64 blocks x 256
  float d[NC]; float tot = 0.0f;
#pragma unroll
  for (int c = 0; c < NC; ++c) { d[c] = cls[c]; tot += d[c]; }
  float rs = 1.0f / sumbuf[row];
  float* op = out + (size_t)row * NC;
#pragma unroll
  for (int c = 0; c < NC; ++c) {
    float den = (d[c] == 0.0f) ? tot : d[c];
    op[c] = op[c] * rs / den;
  }
}

extern "C" void kernel_launch(void* const* d_in, const int* in_sizes, int n_in,
                              void* d_out, int out_size, void* d_ws, size_t ws_size,
                              hipStream_t stream) {
  const float* anchor   = (const float*)d_in[0];  // 6144x128
  const float* positive = (const float*)d_in[1];  // 6144x128
  const float* lbfeat   = (const float*)d_in[2];  // 4096x128
  const float* onehot   = (const float*)d_in[3];  // 4096x10
  const float* l1       = (const float*)d_in[4];  // 6144x10
  const float* l2       = (const float*)d_in[5];  // 6144x10
  float* out = (float*)d_out;                     // 16384x10

  char* ws = (char*)d_ws;
  bf16_t* F      = (bf16_t*)ws;                          // 4 MiB
  float*  V      = (float*)(ws + 4194304);               // 640 KiB
  float*  sumbuf = (float*)(ws + 4194304 + 655360);      // 64 KiB
  float*  cls    = (float*)(ws + 4194304 + 655360 + 65536);  // 64 B

  hipMemsetAsync(sumbuf, 0, 65536 + 64, stream);               // sumbuf + cls
  hipMemsetAsync(out, 0, (size_t)NROWS * NC * sizeof(float), stream);
  knorm<<<NROWS, 64, 0, stream>>>(lbfeat, anchor, positive, F);
  kprep<<<(NLB + NULB) / 256, 256, 0, stream>>>(onehot, l1, l2, V, cls);
  kattn<<<dim3(NROWS / BI, SEG), 512, 0, stream>>>(F, V, out, sumbuf);
  kfinal<<<NROWS / 256, 256, 0, stream>>>(out, sumbuf, cls);
}